// Round 13
// baseline (61.060 us; speedup 1.0000x reference)
//
#include <hip/hip_runtime.h>
#include <hip/hip_bf16.h>

#define BN   8
#define NN   1024
#define CIN  256
#define COUT 256
#define HH   4
#define CC   64
#define ALPHA_C 0.2f

typedef __attribute__((ext_vector_type(8))) short short8;
typedef __attribute__((ext_vector_type(4))) float f32x4;

__device__ __forceinline__ unsigned short f2bf(float x) {
    __hip_bfloat16 h = __float2bfloat16(x);
    return *(unsigned short*)&h;
}
__device__ __forceinline__ float bf2f(unsigned short u) {
    return __uint_as_float(((unsigned int)u) << 16);
}

// ---------------- Kernel 0: pack W (fp32) -> Wh/Wl bf16 panels -----------------------
__global__ __launch_bounds__(256) void k0_wpack(
    const float* __restrict__ W, unsigned short* __restrict__ Whp, unsigned short* __restrict__ Wlp)
{
    const int bid = blockIdx.x;          // kc*4 + jg
    const int n = threadIdx.x;
    const int fi = n * 64 + (bid >> 2) * 8 + (bid & 3) * 2;
    const float4* W4 = (const float4*)W;
    float4 wa = W4[fi], wb = W4[fi + 1];
    float xs[8] = {wa.x, wa.y, wa.z, wa.w, wb.x, wb.y, wb.z, wb.w};
    unsigned short hh[8], ll[8];
    #pragma unroll
    for (int e = 0; e < 8; ++e) {
        hh[e] = f2bf(xs[e]);
        ll[e] = f2bf(xs[e] - bf2f(hh[e]));
    }
    *(uint4*)(Whp + ((size_t)bid * 256 + n) * 8) = *(uint4*)hh;
    *(uint4*)(Wlp + ((size_t)bid * 256 + n) * 8) = *(uint4*)ll;
}

// ---------------- Kernel 1: h = X@W^T + b via bf16x3 MFMA (unchanged) ----------------
__global__ __launch_bounds__(1024, 1) void k1_gemm(
    const float* __restrict__ X, const float* __restrict__ bias, const float* __restrict__ a,
    const unsigned short* __restrict__ Whp, const unsigned short* __restrict__ Wlp,
    unsigned short* __restrict__ hbf_p, float* __restrict__ lsrc_t, float* __restrict__ ldst_t)
{
    __shared__ __align__(16) unsigned short Xh[32 * 256];   // 16 KB, XOR-swizzled
    __shared__ __align__(16) unsigned short Xl[32 * 256];   // 16 KB
    __shared__ float lsP[2][8][2][16];                      // [src/dst][no][mq][m16]

    const int bid = blockIdx.x;
    const int row0 = bid * 32;
    const int b  = bid >> 5;
    const int tj = bid & 31;
    const int tid = threadIdx.x;
    const int wv = tid >> 6, l = tid & 63, il = l & 15, jg = l >> 4;
    const int mq = wv >> 3, no = wv & 7;

    {
        const float4* X4 = (const float4*)(X + (size_t)row0 * CIN);
        #pragma unroll
        for (int it = 0; it < 2; ++it) {
            int f = it * 1024 + tid;            // 0..2047 (32 rows x 64 float4)
            int r = f >> 6, k4 = f & 63;
            float4 x = X4[f];
            unsigned short h0 = f2bf(x.x), h1 = f2bf(x.y), h2 = f2bf(x.z), h3 = f2bf(x.w);
            unsigned short l0 = f2bf(x.x - bf2f(h0)), l1 = f2bf(x.y - bf2f(h1));
            unsigned short l2 = f2bf(x.z - bf2f(h2)), l3 = f2bf(x.w - bf2f(h3));
            unsigned short hs[4] = {h0, h1, h2, h3}, ls[4] = {l0, l1, l2, l3};
            int off = r * 512 + ((k4 * 8) ^ ((r & 7) << 4));
            *(uint2*)((char*)Xh + off) = *(uint2*)hs;
            *(uint2*)((char*)Xl + off) = *(uint2*)ls;
        }
    }
    __syncthreads();

    f32x4 acc0 = {0.f, 0.f, 0.f, 0.f}, acc1 = acc0;
    {
        const int abase = (mq * 16 + il) * 512;
        const int swz = (il & 7) << 4;
        const short8* Wh8 = (const short8*)Whp;
        const short8* Wl8 = (const short8*)Wlp;
        const int nb = no * 32 + il;
        #pragma unroll
        for (int kc = 0; kc < 8; ++kc) {
            const int ab = abase + ((kc * 64 + jg * 16) ^ swz);
            short8 Ah = *(const short8*)((const char*)Xh + ab);
            short8 Al = *(const short8*)((const char*)Xl + ab);
            const int pidx = (kc * 4 + jg) * 256 + nb;
            short8 Bh0 = Wh8[pidx],      Bl0 = Wl8[pidx];
            short8 Bh1 = Wh8[pidx + 16], Bl1 = Wl8[pidx + 16];
            acc0 = __builtin_amdgcn_mfma_f32_16x16x32_bf16(Ah, Bh0, acc0, 0, 0, 0);
            acc1 = __builtin_amdgcn_mfma_f32_16x16x32_bf16(Ah, Bh1, acc1, 0, 0, 0);
            acc0 = __builtin_amdgcn_mfma_f32_16x16x32_bf16(Ah, Bl0, acc0, 0, 0, 0);
            acc1 = __builtin_amdgcn_mfma_f32_16x16x32_bf16(Ah, Bl1, acc1, 0, 0, 0);
            acc0 = __builtin_amdgcn_mfma_f32_16x16x32_bf16(Al, Bh0, acc0, 0, 0, 0);
            acc1 = __builtin_amdgcn_mfma_f32_16x16x32_bf16(Al, Bh1, acc1, 0, 0, 0);
        }
    }

    const int c0 = no * 32 + il, c1 = c0 + 16;
    const float bia0 = bias[c0], bia1 = bias[c1];
    const int hh = no >> 1;
    const int cc0 = c0 & 63, cc1 = c1 & 63;
    const float as0 = a[hh * 128 + cc0],      as1 = a[hh * 128 + cc1];
    const float ad0 = a[hh * 128 + 64 + cc0], ad1 = a[hh * 128 + 64 + cc1];

    float v0[4], v1[4], psrc[4], pdst[4];
    #pragma unroll
    for (int r = 0; r < 4; ++r) {
        v0[r] = acc0[r] + bia0;
        v1[r] = acc1[r] + bia1;
        psrc[r] = v0[r] * as0 + v1[r] * as1;
        pdst[r] = v0[r] * ad0 + v1[r] * ad1;
    }
    #pragma unroll
    for (int off = 8; off >= 1; off >>= 1) {
        #pragma unroll
        for (int r = 0; r < 4; ++r) {
            psrc[r] += __shfl_xor(psrc[r], off);
            pdst[r] += __shfl_xor(pdst[r], off);
        }
    }
    __syncthreads();   // all waves done reading Xh/Xl

    unsigned short* hp = Xh;
    #pragma unroll
    for (int r = 0; r < 4; ++r) {
        int m = mq * 16 + 4 * jg + r;
        int base = (m >> 3) * 128 + (m & 7);
        hp[(c0 >> 6) * 2048 + ((c0 & 63) >> 4) * 512 + base + (c0 & 15) * 8] = f2bf(v0[r]);
        hp[(c1 >> 6) * 2048 + ((c1 & 63) >> 4) * 512 + base + (c1 & 15) * 8] = f2bf(v1[r]);
    }
    if (il == 0) {
        #pragma unroll
        for (int r = 0; r < 4; ++r) {
            lsP[0][no][mq][4 * jg + r] = psrc[r];
            lsP[1][no][mq][4 * jg + r] = pdst[r];
        }
    }
    __syncthreads();

    {
        uint4* dst4 = (uint4*)(hbf_p + (size_t)(b * 32 + tj) * 8192);
        dst4[tid] = ((const uint4*)hp)[tid];
    }
    if (tid < 256) {
        int sd = tid >> 7, rem = tid & 127, h2 = rem >> 5, m = rem & 31;
        float v = lsP[sd][2 * h2][m >> 4][m & 15] + lsP[sd][2 * h2 + 1][m >> 4][m & 15];
        float* dst = sd ? ldst_t : lsrc_t;
        dst[((size_t)b * HH + h2) * NN + tj * 32 + m] = v;
    }
}

// ---------------- Kernel 2: masked softmax attention, PV via MFMA -------------------
// grid 512 x 256thr (4 waves). b = bid&7 (one batch per XCD), i0 = (bid>>3)*16.
// wave = head h; owns 16 rows x its 64 cols x ALL 1024 j (32 panels) -> heads are
// output-disjoint: no cross-wave reduction, ONE barrier total. Live set ~80 VGPR,
// __launch_bounds__(256,2) -> 256-VGPR budget: no spills (r11/r12 failure mode).
// B-frags lane-contiguous 1 KB coalesced; adj = LDS bitmask; ldst = LDS broadcast.
// Rotated 1-tile register prefetch: loads(t+1) issued before PELEM(t) -> full-iter cover.
__global__ __launch_bounds__(256, 2) void k2_attn(
    const unsigned short* __restrict__ hbf_p, const int* __restrict__ adj,
    const float* __restrict__ lsrc_t, const float* __restrict__ ldst_t,
    float* __restrict__ out)
{
    __shared__ unsigned int adjw[32][16];     // [j-word][i-row] bits, 2 KB
    __shared__ float ldsTbl[4 * 1024];        // ldst per head, 16 KB

    const int bid = blockIdx.x;
    const int b  = bid & 7;
    const int i0 = (bid >> 3) * 16;
    const int tid = threadIdx.x;
    const int h  = tid >> 6;                  // wave = head
    const int l  = tid & 63, il = l & 15, jg = l >> 4;

    // ---- prologue: adj bit-pack (wave h packs rows 4h..4h+3) + ldst table ----
    {
        const int* arow = adj + ((size_t)b * NN + i0 + 4 * h) * NN;
        #pragma unroll
        for (int rr = 0; rr < 4; ++rr) {
            #pragma unroll
            for (int it = 0; it < 16; ++it) {
                int av = arow[rr * NN + it * 64 + l];
                unsigned long long mb = __ballot(av != 0);
                if (l == 0) {
                    adjw[2 * it    ][4 * h + rr] = (unsigned int)mb;
                    adjw[2 * it + 1][4 * h + rr] = (unsigned int)(mb >> 32);
                }
            }
        }
    }
    {
        const float4* src = (const float4*)(ldst_t + (size_t)b * HH * NN);
        #pragma unroll
        for (int k = 0; k < 4; ++k)
            ((float4*)ldsTbl)[k * 256 + tid] = src[k * 256 + tid];
    }
    const float lsrc_v = lsrc_t[((size_t)b * HH + h) * NN + i0 + il];

    __syncthreads();   // adjw + ldsTbl ready (only barrier in the kernel)

    // ---- mx = max over all j of ldst[h] (valid softmax shift: lrelu monotone) ----
    float mx = -3.4e38f;
    #pragma unroll
    for (int jt = 0; jt < 16; ++jt) mx = fmaxf(mx, ldsTbl[h * 1024 + jt * 64 + l]);
    #pragma unroll
    for (int off = 32; off >= 1; off >>= 1) mx = fmaxf(mx, __shfl_xor(mx, off));
    const float t0  = lsrc_v + mx;
    const float m_r = fmaxf(t0, ALPHA_C * t0);
    float lsum = 0.f;

    f32x4 acc0 = {0.f,0.f,0.f,0.f}, acc1 = acc0, acc2 = acc0, acc3 = acc0;

    // B-frag: panel t, head h, sub s, lane l at short8 index t*1024 + h*256 + s*64 + l
    const short8* bfp = (const short8*)(hbf_p + (size_t)b * 32 * 8192);
    const int fb = h * 256 + l;

    short8 c0 = bfp[fb +   0];
    short8 c1 = bfp[fb +  64];
    short8 c2 = bfp[fb + 128];
    short8 c3 = bfp[fb + 192];

    #pragma unroll 2
    for (int t = 0; t < 32; ++t) {
        // ---- issue next tile's coalesced loads first (consumed next iter) ----
        const int tn = (t < 31) ? t + 1 : 31;
        short8 n0 = bfp[tn * 1024 + fb +   0];
        short8 n1 = bfp[tn * 1024 + fb +  64];
        short8 n2 = bfp[tn * 1024 + fb + 128];
        short8 n3 = bfp[tn * 1024 + fb + 192];

        // ---- P from adj bits + ldst broadcasts (independent of the loads) ----
        const unsigned int bw = adjw[t][il] >> (jg * 8);
        const float* lt = ldsTbl + h * 1024 + t * 32 + jg * 8;
        const float4 dA = *(const float4*)lt;
        const float4 dB = *(const float4*)(lt + 4);
        short8 af;
        #define PELEM(DV, E) {                                   \
            float s_ = lsrc_v + (DV);                            \
            s_ = fmaxf(s_, ALPHA_C * s_);                        \
            float p_ = __expf(s_ - m_r);                         \
            p_ = ((bw >> (E)) & 1u) ? p_ : 0.f;                  \
            lsum += p_;                                          \
            af[E] = (short)f2bf(p_); }
        PELEM(dA.x, 0) PELEM(dA.y, 1) PELEM(dA.z, 2) PELEM(dA.w, 3)
        PELEM(dB.x, 4) PELEM(dB.y, 5) PELEM(dB.z, 6) PELEM(dB.w, 7)
        #undef PELEM

        acc0 = __builtin_amdgcn_mfma_f32_16x16x32_bf16(af, c0, acc0, 0, 0, 0);
        acc1 = __builtin_amdgcn_mfma_f32_16x16x32_bf16(af, c1, acc1, 0, 0, 0);
        acc2 = __builtin_amdgcn_mfma_f32_16x16x32_bf16(af, c2, acc2, 0, 0, 0);
        acc3 = __builtin_amdgcn_mfma_f32_16x16x32_bf16(af, c3, acc3, 0, 0, 0);

        c0 = n0; c1 = n1; c2 = n2; c3 = n3;
    }

    // ---- lsum: reduce across jg groups; lane x holds total for row x&15 ----
    lsum += __shfl_xor(lsum, 16);
    lsum += __shfl_xor(lsum, 32);

    float inv[4];
    #pragma unroll
    for (int r = 0; r < 4; ++r) inv[r] = 1.0f / __shfl(lsum, 4 * jg + r);

    // ---- store: D row = 4*jg+r, col = il; head h owns cols h*64..h*64+63 ----
    float* outp = out + ((size_t)b * NN + i0) * COUT + h * 64 + il;
    #pragma unroll
    for (int r = 0; r < 4; ++r) {
        const size_t ro = (size_t)(4 * jg + r) * COUT;
        outp[ro +  0] = acc0[r] * inv[r];
        outp[ro + 16] = acc1[r] * inv[r];
        outp[ro + 32] = acc2[r] * inv[r];
        outp[ro + 48] = acc3[r] * inv[r];
    }
}

extern "C" void kernel_launch(void* const* d_in, const int* in_sizes, int n_in,
                              void* d_out, int out_size, void* d_ws, size_t ws_size,
                              hipStream_t stream) {
    const float* X    = (const float*)d_in[0];
    const int*   adj  = (const int*)  d_in[1];
    const float* W    = (const float*)d_in[2];
    const float* bias = (const float*)d_in[3];
    const float* a    = (const float*)d_in[4];
    float* out = (float*)d_out;

    unsigned short* hbf_p = (unsigned short*)d_ws;                  // 8*32 panels, 4 MB
    float* lsrc_t = (float*)(hbf_p + (size_t)BN * 32 * 8192);       // [b][h][n]
    float* ldst_t = lsrc_t + (size_t)BN * HH * NN;
    unsigned short* Whp = (unsigned short*)(ldst_t + (size_t)BN * HH * NN);  // 128 KB
    unsigned short* Wlp = Whp + 65536;                                        // 128 KB

    k0_wpack<<<32, 256, 0, stream>>>(W, Whp, Wlp);
    k1_gemm<<<256, 1024, 0, stream>>>(X, bias, a, Whp, Wlp, hbf_p, lsrc_t, ldst_t);
    k2_attn<<<BN * (NN / 16), 256, 0, stream>>>(hbf_p, adj, lsrc_t, ldst_t, out);
}